// Round 8
// baseline (791.619 us; speedup 1.0000x reference)
//
#include <hip/hip_runtime.h>

typedef _Float16 f16;
typedef _Float16 f16x2 __attribute__((ext_vector_type(2)));
typedef _Float16 f16x4 __attribute__((ext_vector_type(4)));
typedef _Float16 f16x8 __attribute__((ext_vector_type(8)));
typedef float    f32x4 __attribute__((ext_vector_type(4)));

constexpr int B_ = 2, H_ = 16, T_ = 2048, D_ = 64, R_ = 32, NT = 32;
constexpr int NROW = B_ * H_ * T_;   // 65536 (bh,t) rows

__device__ __forceinline__ f32x4 mfma16(f16x8 a, f16x8 b, f32x4 c) {
  return __builtin_amdgcn_mfma_f32_16x16x32_f16(a, b, c, 0, 0, 0);
}
__device__ __forceinline__ void ld_lds16(const void* g, void* l) {
  __builtin_amdgcn_global_load_lds(
      (const __attribute__((address_space(1))) unsigned int*)g,
      (__attribute__((address_space(3))) unsigned int*)l, 16, 0, 0);
}

// ---------------- Kernel A: MFMA projections + swizzled V^T (R7) ----------------
// Also zeroes the 1024 split-merge counters (blocks 0-3) so no extra memset
// dispatch is needed; kernel-boundary ordering makes them visible to attn.
__global__ __launch_bounds__(256) void proj_kernel(
    const float* __restrict__ q, const float* __restrict__ k, const float* __restrict__ v,
    const float* __restrict__ Wq, const float* __restrict__ Wk,
    const float* __restrict__ c1, const float* __restrict__ c2,
    f16* __restrict__ qlr, f16* __restrict__ klr, f16* __restrict__ vt,
    int* __restrict__ cnt)
{
  __shared__ float sv[64 * 65];                    // 16.6 KB V transpose
  __shared__ __align__(16) f16 s_w[2][32 * 64];    //  8 KB W^T [mat][r][d-swz]
  __shared__ __align__(16) f16 s_qk[2][64 * 32];   //  8 KB [mat][row][r]

  const int tid = threadIdx.x, w = tid >> 6, lane = tid & 63;
  const int l15 = lane & 15, l4 = lane >> 4;
  const int bh = blockIdx.x >> 5, h = bh & (H_ - 1);
  const int t0 = (blockIdx.x & 31) * 64;

  if (blockIdx.x < 4) cnt[blockIdx.x * 256 + tid] = 0;

  const float* vb = v + ((size_t)bh * T_ + t0) * D_;
  float4 vld[4];
#pragma unroll
  for (int it = 0; it < 4; ++it) vld[it] = ((const float4*)vb)[it * 256 + tid];

  const int m = t0 + 16 * w + l15;
  const float* qr = q + ((size_t)bh * T_ + m) * D_;
  const float* kr = k + ((size_t)bh * T_ + m) * D_;
  f16x8 aq[2], ak[2];
#pragma unroll
  for (int kc = 0; kc < 2; ++kc) {
    float4 x0 = *(const float4*)(qr + kc * 32 + 8 * l4);
    float4 x1 = *(const float4*)(qr + kc * 32 + 8 * l4 + 4);
    float4 y0 = *(const float4*)(kr + kc * 32 + 8 * l4);
    float4 y1 = *(const float4*)(kr + kc * 32 + 8 * l4 + 4);
    f16x8 A, K;
    A[0]=(f16)x0.x; A[1]=(f16)x0.y; A[2]=(f16)x0.z; A[3]=(f16)x0.w;
    A[4]=(f16)x1.x; A[5]=(f16)x1.y; A[6]=(f16)x1.z; A[7]=(f16)x1.w;
    K[0]=(f16)y0.x; K[1]=(f16)y0.y; K[2]=(f16)y0.z; K[3]=(f16)y0.w;
    K[4]=(f16)y1.x; K[5]=(f16)y1.y; K[6]=(f16)y1.z; K[7]=(f16)y1.w;
    aq[kc] = A; ak[kc] = K;
  }

  // ---- W -> LDS, transposed + swizzled: elem (r,d) at r*64 + ((d>>3)^(r&7))*8 + (d&7)
  const float* Wqh = Wq + (size_t)h * D_ * R_;
  const float* Wkh = Wk + (size_t)h * D_ * R_;
#pragma unroll
  for (int mm = 0; mm < 2; ++mm) {
    const float* Wh = mm ? Wkh : Wqh;
#pragma unroll
    for (int it = 0; it < 2; ++it) {
      const int flat = it * 1024 + tid * 4;        // = d*32 + r, 4 consecutive r
      const int d = flat >> 5, r = flat & 31;
      const float4 wv = *(const float4*)(Wh + flat);
#pragma unroll
      for (int e = 0; e < 4; ++e) {
        const int rr = r + e;
        s_w[mm][rr * 64 + ((((d >> 3) ^ (rr & 7)) << 3) | (d & 7))] = (f16)((&wv.x)[e]);
      }
    }
  }

#pragma unroll
  for (int it = 0; it < 4; ++it) {
    const int i4 = it * 256 + tid, t = i4 >> 4, dq = (i4 & 15) * 4;
    sv[t * 65 + dq    ] = vld[it].x;
    sv[t * 65 + dq + 1] = vld[it].y;
    sv[t * 65 + dq + 2] = vld[it].z;
    sv[t * 65 + dq + 3] = vld[it].w;
  }

  __syncthreads();   // covers s_w and sv

  f16x8 bq[2][2], bk[2][2];
#pragma unroll
  for (int kc = 0; kc < 2; ++kc)
#pragma unroll
    for (int nt = 0; nt < 2; ++nt) {
      const int r = 16 * nt + l15;
      const int d0 = kc * 32 + 8 * l4;
      const int idx = r * 64 + (((d0 >> 3) ^ (r & 7)) << 3);
      bq[kc][nt] = *(const f16x8*)&s_w[0][idx];
      bk[kc][nt] = *(const f16x8*)&s_w[1][idx];
    }

  const f32x4 z4 = {0.f, 0.f, 0.f, 0.f};
#pragma unroll
  for (int nt = 0; nt < 2; ++nt) {
    f32x4 accq = mfma16(aq[0], bq[0][nt], z4);
    accq = mfma16(aq[1], bq[1][nt], accq);
    f32x4 acck = mfma16(ak[0], bk[0][nt], z4);
    acck = mfma16(ak[1], bk[1][nt], acck);
    const int r = 16 * nt + l15;
    const float scl = c1[h * 4 + (r >> 3)] * c2[h * 8 + (r & 7)] *
                      (0.17677669529663687f * 1.4426950408889634f);
#pragma unroll
    for (int i = 0; i < 4; ++i) {
      const int lrow = 16 * w + 4 * l4 + i;          // local row 0..63
      s_qk[0][lrow * 32 + r] = (f16)(accq[i] * scl);
      s_qk[1][lrow * 32 + r] = (f16)acck[i];
    }
  }

  // vt stores (read sv; safe after first barrier)
#pragma unroll
  for (int it = 0; it < 8; ++it) {
    const int idx = it * 256 + tid, d = idx >> 5, t = (idx & 31) * 2;
    const float f0 = sv[t * 65 + d], f1 = sv[t * 65 + 65 + d];
    f16x2 pr; pr[0] = (f16)f0; pr[1] = (f16)f1;
    const int sw = ((((t >> 3) ^ (d & 7)) << 3) | (t & 7));
    *(f16x2*)(vt + ((size_t)bh * D_ + d) * T_ + t0 + sw) = pr;
  }

  __syncthreads();   // covers s_qk

  const int lrow = tid >> 2;
  const int r0 = (tid & 3) * 8;
  const f16x8 vq = *(const f16x8*)&s_qk[0][lrow * 32 + r0];
  *(f16x8*)(qlr + ((size_t)bh * T_ + t0 + lrow) * R_ + r0) = vq;
  const f16x8 vk = *(const f16x8*)&s_qk[1][lrow * 32 + r0];
  *(f16x8*)(klr + ((size_t)bh * T_ + t0 + lrow) * R_ + r0) = vk;
}

// ---------------- Kernel B: flash attention + fused split-merge ----------------
// Compute loop = R5/R7 verbatim (best measured, 44.7us). New epilogue: after
// writing normalized partials, fence + per-(bh,mt) atomic counter; the last
// of the NS split-blocks acquires and performs the (former merge_kernel) math
// for its 64 rows, writing `out` directly. Kernel count 3 -> 2; merge work
// overlaps residual attn compute. No min-waves launch_bounds (R2 lesson).
__global__ __launch_bounds__(256) void attn_kernel(
    const f16* __restrict__ qlr, const f16* __restrict__ klr,
    const f16* __restrict__ vt, f16* __restrict__ On, float2* __restrict__ ml,
    float* __restrict__ out, int* __restrict__ cnt, const int NS)
{
  __shared__ __align__(16) f16 s_k[64 * 32];       // 4KB [n][r]
  __shared__ __align__(16) f16 s_vt[64 * 64];      // 8KB [d][n-swizzled]
  __shared__ __align__(16) f16 s_p[4][16 * 64];    // 8KB per-wave [m][n-swizzled]

  const int tid = threadIdx.x, w = tid >> 6, lane = tid & 63;
  const int l15 = lane & 15, l4 = lane >> 4;
  const int bh = blockIdx.x & 31;
  const int rest = blockIdx.x >> 5;
  const int nsl = (NS == 4) ? 2 : (NS == 2) ? 1 : 0;
  const int mt = 31 - (rest >> nsl);     // longest-first dispatch
  const int s  = rest & (NS - 1);
  const int m0 = mt * 64;

  const f16x8 aq = *(const f16x8*)(qlr + ((size_t)bh * T_ + m0 + 16 * w + l15) * R_ + 8 * l4);

  const f16* kb = klr + (size_t)bh * T_ * R_;
  const f16* vb = vt + (size_t)bh * D_ * T_;

  const f32x4 z4 = {0.f, 0.f, 0.f, 0.f};
  f32x4 oacc[4];
#pragma unroll
  for (int d = 0; d < 4; ++d) oacc[d] = z4;
  float mi = -1e30f, li = 0.f;

  for (int j = s; j <= mt; j += NS) {
    const int n0 = 64 * j;
    __syncthreads();
    ld_lds16((const char*)kb + (size_t)n0 * 64 + w * 1024 + lane * 16,
             (char*)s_k + w * 1024);
#pragma unroll
    for (int e = 0; e < 2; ++e) {
      const int d0 = 16 * w + e * 8;
      ld_lds16((const char*)vb + ((size_t)(d0 + (lane >> 3)) * T_ + n0) * 2 + (lane & 7) * 16,
               (char*)s_vt + d0 * 128);
    }
    __syncthreads();

    f32x4 sc[4];
#pragma unroll
    for (int ns = 0; ns < 4; ++ns) {
      f16x8 akf = *(const f16x8*)&s_k[(16 * ns + l15) * 32 + 8 * l4];
      sc[ns] = mfma16(akf, aq, z4);
    }
    if (j == mt) {
      const int lim = 16 * w + l15;
#pragma unroll
      for (int ns = 0; ns < 4; ++ns) {
        const int nb = 16 * ns + 4 * l4;
#pragma unroll
        for (int i = 0; i < 4; ++i)
          if (nb + i > lim) sc[ns][i] = -1e30f;
      }
    }

    float rm = -1e30f;
#pragma unroll
    for (int ns = 0; ns < 4; ++ns)
#pragma unroll
      for (int i = 0; i < 4; ++i) rm = fmaxf(rm, sc[ns][i]);
    rm = fmaxf(rm, __shfl_xor(rm, 16));
    rm = fmaxf(rm, __shfl_xor(rm, 32));
    const float mn = fmaxf(mi, rm);
    const float a = exp2f(mi - mn);
    float rs = 0.f;
#pragma unroll
    for (int ns = 0; ns < 4; ++ns) {
      f16x4 pf;
#pragma unroll
      for (int i = 0; i < 4; ++i) {
        const float p = exp2f(sc[ns][i] - mn);
        rs += p; pf[i] = (f16)p;
      }
      const int col = ((((2 * ns + (l4 >> 1)) ^ (l15 & 7)) << 3) | (4 * (l4 & 1)));
      *(f16x4*)&s_p[w][l15 * 64 + col] = pf;
    }
    rs += __shfl_xor(rs, 16);
    rs += __shfl_xor(rs, 32);
    li = li * a + rs; mi = mn;
#pragma unroll
    for (int d = 0; d < 4; ++d) oacc[d] *= a;

#pragma unroll
    for (int nk = 0; nk < 2; ++nk) {
      const int u = (4 * nk + l4) ^ (l15 & 7);
      f16x8 bp = *(const f16x8*)&s_p[w][l15 * 64 + u * 8];
#pragma unroll
      for (int dblk = 0; dblk < 4; ++dblk) {
        f16x8 av = *(const f16x8*)&s_vt[(16 * dblk + l15) * 64 + u * 8];
        oacc[dblk] = mfma16(av, bp, oacc[dblk]);
      }
    }
  }

  // ---- epilogue: normalized partial O (f16) + (m,l) ----
  const float invl = li > 0.f ? 1.f / li : 0.f;   // empty split -> zeros, no NaN
  f16* ob = On + (((size_t)s * 32 + bh) * T_ + m0 + 16 * w + l15) * D_;
#pragma unroll
  for (int dblk = 0; dblk < 4; ++dblk) {
    f16x4 o;
#pragma unroll
    for (int i = 0; i < 4; ++i) o[i] = (f16)(oacc[dblk][i] * invl);
    *(f16x4*)(ob + 16 * dblk + 4 * l4) = o;
  }
  if (l4 == 0) {
    float2 mlv; mlv.x = mi; mlv.y = li;
    ml[((size_t)s * 32 + bh) * T_ + m0 + 16 * w + l15] = mlv;
  }

  // ---- fused split-merge: last-arriving block per (bh,mt) merges ----
  int* s_flag = (int*)&s_p[0][0];
  __threadfence();                       // release partials (all threads)
  __syncthreads();                       // all threads' stores + fences done
  if (tid == 0) {
    const int old = atomicAdd(&cnt[bh * 32 + mt], 1);
    s_flag[0] = (old == NS - 1) ? 1 : 0;
  }
  __syncthreads();
  if (s_flag[0]) {
    __threadfence();                     // acquire other splits' partials
    const int rl = tid >> 2;             // 0..63 local row
    const int dq = (tid & 3) * 16;       // 0,16,32,48
    const size_t rloc = (size_t)m0 + rl; // row within bh
    float2 mlv[4];
    float mx = -1e30f;
#pragma unroll
    for (int p = 0; p < 4; ++p) {
      if (p < NS) mlv[p] = ml[((size_t)p * 32 + bh) * T_ + rloc];
      else { mlv[p].x = -1e30f; mlv[p].y = 0.f; }
      mx = fmaxf(mx, mlv[p].x);
    }
    float c[4], wsum = 0.f;
#pragma unroll
    for (int p = 0; p < 4; ++p) { c[p] = exp2f(mlv[p].x - mx) * mlv[p].y; wsum += c[p]; }
    const float inv = 1.f / wsum;
#pragma unroll
    for (int p = 0; p < 4; ++p) c[p] *= inv;
    float* obp = out + ((size_t)bh * T_ + rloc) * 64 + dq;
#pragma unroll
    for (int half = 0; half < 2; ++half) {
      float res[8];
#pragma unroll
      for (int e = 0; e < 8; ++e) res[e] = 0.f;
#pragma unroll
      for (int p = 0; p < 4; ++p) {
        if (p < NS) {
          const f16x8 o8 = *(const f16x8*)(On + (((size_t)p * 32 + bh) * T_ + rloc) * 64 + dq + 8 * half);
#pragma unroll
          for (int e = 0; e < 8; ++e) res[e] += c[p] * (float)o8[e];
        }
      }
      f32x4 r0, r1;
#pragma unroll
      for (int e = 0; e < 4; ++e) { r0[e] = res[e]; r1[e] = res[4 + e]; }
      *(f32x4*)(obp + 8 * half) = r0;
      *(f32x4*)(obp + 8 * half + 4) = r1;
    }
  }
}

extern "C" void kernel_launch(void* const* d_in, const int* in_sizes, int n_in,
                              void* d_out, int out_size, void* d_ws, size_t ws_size,
                              hipStream_t stream) {
  const float* q  = (const float*)d_in[0];
  const float* k  = (const float*)d_in[1];
  const float* v  = (const float*)d_in[2];
  const float* Wq = (const float*)d_in[3];
  const float* Wk = (const float*)d_in[4];
  const float* c1 = (const float*)d_in[5];
  const float* c2 = (const float*)d_in[6];
  float* out = (float*)d_out;

  const size_t MB = 1 << 20;
  // proj area 16 MiB; per split: On 8 MiB + ml 0.5 MiB; + 4 KiB counters
  int NS = 1;
  if (ws_size >= 16 * MB + 4 * (8 * MB + NROW * sizeof(float2)) + 4096) NS = 4;
  else if (ws_size >= 16 * MB + 2 * (8 * MB + NROW * sizeof(float2)) + 4096) NS = 2;

  f16* qlr = (f16*)d_ws;                                   // 4 MiB
  f16* klr = qlr + (size_t)B_ * H_ * T_ * R_;              // 4 MiB
  f16* vt  = klr + (size_t)B_ * H_ * T_ * R_;              // 8 MiB
  f16* On  = vt + (size_t)B_ * H_ * T_ * D_;               // NS * 8 MiB
  float2* ml = (float2*)(On + (size_t)NS * NROW * D_);     // NS * 0.5 MiB
  int* cnt = (int*)(ml + (size_t)NS * NROW);               // 4 KiB counters

  proj_kernel<<<B_ * H_ * NT, 256, 0, stream>>>(q, k, v, Wq, Wk, c1, c2, qlr, klr, vt, cnt);
  attn_kernel<<<B_ * H_ * NT * NS, 256, 0, stream>>>(qlr, klr, vt, On, ml, out, cnt, NS);
}

// Round 9
// 141.791 us; speedup vs baseline: 5.5830x; 5.5830x over previous
//
#include <hip/hip_runtime.h>

typedef _Float16 f16;
typedef _Float16 f16x2 __attribute__((ext_vector_type(2)));
typedef _Float16 f16x4 __attribute__((ext_vector_type(4)));
typedef _Float16 f16x8 __attribute__((ext_vector_type(8)));
typedef float    f32x4 __attribute__((ext_vector_type(4)));

constexpr int B_ = 2, H_ = 16, T_ = 2048, D_ = 64, R_ = 32, NT = 32;
constexpr int NROW = B_ * H_ * T_;   // 65536 (bh,t) rows

__device__ __forceinline__ f32x4 mfma16(f16x8 a, f16x8 b, f32x4 c) {
  return __builtin_amdgcn_mfma_f32_16x16x32_f16(a, b, c, 0, 0, 0);
}
__device__ __forceinline__ void ld_lds16(const void* g, void* l) {
  __builtin_amdgcn_global_load_lds(
      (const __attribute__((address_space(1))) unsigned int*)g,
      (__attribute__((address_space(3))) unsigned int*)l, 16, 0, 0);
}

// ---------------- Kernel A: MFMA projections + swizzled V^T (R7 verbatim) ----------------
__global__ __launch_bounds__(256) void proj_kernel(
    const float* __restrict__ q, const float* __restrict__ k, const float* __restrict__ v,
    const float* __restrict__ Wq, const float* __restrict__ Wk,
    const float* __restrict__ c1, const float* __restrict__ c2,
    f16* __restrict__ qlr, f16* __restrict__ klr, f16* __restrict__ vt)
{
  __shared__ float sv[64 * 65];                    // 16.6 KB V transpose
  __shared__ __align__(16) f16 s_w[2][32 * 64];    //  8 KB W^T [mat][r][d-swz]
  __shared__ __align__(16) f16 s_qk[2][64 * 32];   //  8 KB [mat][row][r]

  const int tid = threadIdx.x, w = tid >> 6, lane = tid & 63;
  const int l15 = lane & 15, l4 = lane >> 4;
  const int bh = blockIdx.x >> 5, h = bh & (H_ - 1);
  const int t0 = (blockIdx.x & 31) * 64;

  const float* vb = v + ((size_t)bh * T_ + t0) * D_;
  float4 vld[4];
#pragma unroll
  for (int it = 0; it < 4; ++it) vld[it] = ((const float4*)vb)[it * 256 + tid];

  const int m = t0 + 16 * w + l15;
  const float* qr = q + ((size_t)bh * T_ + m) * D_;
  const float* kr = k + ((size_t)bh * T_ + m) * D_;
  f16x8 aq[2], ak[2];
#pragma unroll
  for (int kc = 0; kc < 2; ++kc) {
    float4 x0 = *(const float4*)(qr + kc * 32 + 8 * l4);
    float4 x1 = *(const float4*)(qr + kc * 32 + 8 * l4 + 4);
    float4 y0 = *(const float4*)(kr + kc * 32 + 8 * l4);
    float4 y1 = *(const float4*)(kr + kc * 32 + 8 * l4 + 4);
    f16x8 A, K;
    A[0]=(f16)x0.x; A[1]=(f16)x0.y; A[2]=(f16)x0.z; A[3]=(f16)x0.w;
    A[4]=(f16)x1.x; A[5]=(f16)x1.y; A[6]=(f16)x1.z; A[7]=(f16)x1.w;
    K[0]=(f16)y0.x; K[1]=(f16)y0.y; K[2]=(f16)y0.z; K[3]=(f16)y0.w;
    K[4]=(f16)y1.x; K[5]=(f16)y1.y; K[6]=(f16)y1.z; K[7]=(f16)y1.w;
    aq[kc] = A; ak[kc] = K;
  }

  // ---- W -> LDS, transposed + swizzled: elem (r,d) at r*64 + ((d>>3)^(r&7))*8 + (d&7)
  const float* Wqh = Wq + (size_t)h * D_ * R_;
  const float* Wkh = Wk + (size_t)h * D_ * R_;
#pragma unroll
  for (int mm = 0; mm < 2; ++mm) {
    const float* Wh = mm ? Wkh : Wqh;
#pragma unroll
    for (int it = 0; it < 2; ++it) {
      const int flat = it * 1024 + tid * 4;        // = d*32 + r, 4 consecutive r
      const int d = flat >> 5, r = flat & 31;
      const float4 wv = *(const float4*)(Wh + flat);
#pragma unroll
      for (int e = 0; e < 4; ++e) {
        const int rr = r + e;
        s_w[mm][rr * 64 + ((((d >> 3) ^ (rr & 7)) << 3) | (d & 7))] = (f16)((&wv.x)[e]);
      }
    }
  }

#pragma unroll
  for (int it = 0; it < 4; ++it) {
    const int i4 = it * 256 + tid, t = i4 >> 4, dq = (i4 & 15) * 4;
    sv[t * 65 + dq    ] = vld[it].x;
    sv[t * 65 + dq + 1] = vld[it].y;
    sv[t * 65 + dq + 2] = vld[it].z;
    sv[t * 65 + dq + 3] = vld[it].w;
  }

  __syncthreads();   // covers s_w and sv

  f16x8 bq[2][2], bk[2][2];
#pragma unroll
  for (int kc = 0; kc < 2; ++kc)
#pragma unroll
    for (int nt = 0; nt < 2; ++nt) {
      const int r = 16 * nt + l15;
      const int d0 = kc * 32 + 8 * l4;
      const int idx = r * 64 + (((d0 >> 3) ^ (r & 7)) << 3);
      bq[kc][nt] = *(const f16x8*)&s_w[0][idx];
      bk[kc][nt] = *(const f16x8*)&s_w[1][idx];
    }

  const f32x4 z4 = {0.f, 0.f, 0.f, 0.f};
#pragma unroll
  for (int nt = 0; nt < 2; ++nt) {
    f32x4 accq = mfma16(aq[0], bq[0][nt], z4);
    accq = mfma16(aq[1], bq[1][nt], accq);
    f32x4 acck = mfma16(ak[0], bk[0][nt], z4);
    acck = mfma16(ak[1], bk[1][nt], acck);
    const int r = 16 * nt + l15;
    const float scl = c1[h * 4 + (r >> 3)] * c2[h * 8 + (r & 7)] *
                      (0.17677669529663687f * 1.4426950408889634f);
#pragma unroll
    for (int i = 0; i < 4; ++i) {
      const int lrow = 16 * w + 4 * l4 + i;          // local row 0..63
      s_qk[0][lrow * 32 + r] = (f16)(accq[i] * scl);
      s_qk[1][lrow * 32 + r] = (f16)acck[i];
    }
  }

  // vt stores (read sv; safe after first barrier)
#pragma unroll
  for (int it = 0; it < 8; ++it) {
    const int idx = it * 256 + tid, d = idx >> 5, t = (idx & 31) * 2;
    const float f0 = sv[t * 65 + d], f1 = sv[t * 65 + 65 + d];
    f16x2 pr; pr[0] = (f16)f0; pr[1] = (f16)f1;
    const int sw = ((((t >> 3) ^ (d & 7)) << 3) | (t & 7));
    *(f16x2*)(vt + ((size_t)bh * D_ + d) * T_ + t0 + sw) = pr;
  }

  __syncthreads();   // covers s_qk

  const int lrow = tid >> 2;
  const int r0 = (tid & 3) * 8;
  const f16x8 vq = *(const f16x8*)&s_qk[0][lrow * 32 + r0];
  *(f16x8*)(qlr + ((size_t)bh * T_ + t0 + lrow) * R_ + r0) = vq;
  const f16x8 vk = *(const f16x8*)&s_qk[1][lrow * 32 + r0];
  *(f16x8*)(klr + ((size_t)bh * T_ + t0 + lrow) * R_ + r0) = vk;
}

// ---------------- Kernel B: flash attention, m-split only, direct output ----------------
// R8 lesson: intra-kernel cross-XCD merge needs per-block L2 writeback fences
// (17x regression); kernel-boundary flush is the only cheap handoff. R0-R7
// accounting: the merge kernel + 3rd graph node costs ~65-70us regardless of
// its traffic. So: NS=1 (m-split only) -> NO merge, NO On/ml roundtrip; each
// block (bh,mt) runs its full causal range and writes f32 `out` directly
// (drops the f16 partial rounding -> slightly MORE accurate).
// Compute loop = R5/R7 verbatim (best measured). Tail risk priced: mt=31
// chains ~32 iters; expected attn 55-70us, net win if merge-cost theory holds.
// No min-waves launch_bounds (R2 spill lesson).
__global__ __launch_bounds__(256) void attn_kernel(
    const f16* __restrict__ qlr, const f16* __restrict__ klr,
    const f16* __restrict__ vt, float* __restrict__ out)
{
  __shared__ __align__(16) f16 s_k[64 * 32];       // 4KB [n][r]
  __shared__ __align__(16) f16 s_vt[64 * 64];      // 8KB [d][n-swizzled]
  __shared__ __align__(16) f16 s_p[4][16 * 64];    // 8KB per-wave [m][n-swizzled]

  const int tid = threadIdx.x, w = tid >> 6, lane = tid & 63;
  const int l15 = lane & 15, l4 = lane >> 4;
  const int bh = blockIdx.x & 31;
  const int mt = 31 - (blockIdx.x >> 5);   // longest-first dispatch
  const int m0 = mt * 64;

  // wave w owns m-rows [m0+16w, m0+16w+16); per-lane m = l15 (4 l4-dup groups)
  const f16x8 aq = *(const f16x8*)(qlr + ((size_t)bh * T_ + m0 + 16 * w + l15) * R_ + 8 * l4);

  const f16* kb = klr + (size_t)bh * T_ * R_;
  const f16* vb = vt + (size_t)bh * D_ * T_;

  const f32x4 z4 = {0.f, 0.f, 0.f, 0.f};
  f32x4 oacc[4];
#pragma unroll
  for (int d = 0; d < 4; ++d) oacc[d] = z4;
  float mi = -1e30f, li = 0.f;

  for (int j = 0; j <= mt; ++j) {
    const int n0 = 64 * j;
    __syncthreads();
    // stage K: wave w covers rows 16w..16w+15 (1KB, rows contiguous 64B)
    ld_lds16((const char*)kb + (size_t)n0 * 64 + w * 1024 + lane * 16,
             (char*)s_k + w * 1024);
    // stage V^T: wave w covers d = 16w .. 16w+15 (2 x 1KB)
#pragma unroll
    for (int e = 0; e < 2; ++e) {
      const int d0 = 16 * w + e * 8;
      ld_lds16((const char*)vb + ((size_t)(d0 + (lane >> 3)) * T_ + n0) * 2 + (lane & 7) * 16,
               (char*)s_vt + d0 * 128);
    }
    __syncthreads();

    // QK^T: sc[ns][i] = score(n = 16ns+4l4+i, m = l15)
    f32x4 sc[4];
#pragma unroll
    for (int ns = 0; ns < 4; ++ns) {
      f16x8 akf = *(const f16x8*)&s_k[(16 * ns + l15) * 32 + 8 * l4];
      sc[ns] = mfma16(akf, aq, z4);
    }
    if (j == mt) {
      const int lim = 16 * w + l15;
#pragma unroll
      for (int ns = 0; ns < 4; ++ns) {
        const int nb = 16 * ns + 4 * l4;
#pragma unroll
        for (int i = 0; i < 4; ++i)
          if (nb + i > lim) sc[ns][i] = -1e30f;
      }
    }

    float rm = -1e30f;
#pragma unroll
    for (int ns = 0; ns < 4; ++ns)
#pragma unroll
      for (int i = 0; i < 4; ++i) rm = fmaxf(rm, sc[ns][i]);
    rm = fmaxf(rm, __shfl_xor(rm, 16));
    rm = fmaxf(rm, __shfl_xor(rm, 32));
    const float mn = fmaxf(mi, rm);
    const float a = exp2f(mi - mn);
    float rs = 0.f;
#pragma unroll
    for (int ns = 0; ns < 4; ++ns) {
      f16x4 pf;
#pragma unroll
      for (int i = 0; i < 4; ++i) {
        const float p = exp2f(sc[ns][i] - mn);
        rs += p; pf[i] = (f16)p;
      }
      // store P[m=l15][n=16ns+4l4+i], n-block XOR-swizzled by (m&7)
      const int col = ((((2 * ns + (l4 >> 1)) ^ (l15 & 7)) << 3) | (4 * (l4 & 1)));
      *(f16x4*)&s_p[w][l15 * 64 + col] = pf;
    }
    rs += __shfl_xor(rs, 16);
    rs += __shfl_xor(rs, 32);
    li = li * a + rs; mi = mn;
#pragma unroll
    for (int d = 0; d < 4; ++d) oacc[d] *= a;

    // PV: O(m=l15, d=16dblk+4l4+i) += sum_n P[m][n] * V^T[d][n]
#pragma unroll
    for (int nk = 0; nk < 2; ++nk) {
      const int u = (4 * nk + l4) ^ (l15 & 7);   // un-swizzle n-block 4nk+l4
      f16x8 bp = *(const f16x8*)&s_p[w][l15 * 64 + u * 8];
#pragma unroll
      for (int dblk = 0; dblk < 4; ++dblk) {
        f16x8 av = *(const f16x8*)&s_vt[(16 * dblk + l15) * 64 + u * 8];
        oacc[dblk] = mfma16(av, bp, oacc[dblk]);
      }
    }
  }

  // ---- epilogue: final normalize, direct f32 output ----
  const float invl = li > 0.f ? 1.f / li : 0.f;
  float* ob = out + ((size_t)bh * T_ + m0 + 16 * w + l15) * D_;
#pragma unroll
  for (int dblk = 0; dblk < 4; ++dblk) {
    f32x4 o;
#pragma unroll
    for (int i = 0; i < 4; ++i) o[i] = oacc[dblk][i] * invl;
    *(f32x4*)(ob + 16 * dblk + 4 * l4) = o;
  }
}

extern "C" void kernel_launch(void* const* d_in, const int* in_sizes, int n_in,
                              void* d_out, int out_size, void* d_ws, size_t ws_size,
                              hipStream_t stream) {
  const float* q  = (const float*)d_in[0];
  const float* k  = (const float*)d_in[1];
  const float* v  = (const float*)d_in[2];
  const float* Wq = (const float*)d_in[3];
  const float* Wk = (const float*)d_in[4];
  const float* c1 = (const float*)d_in[5];
  const float* c2 = (const float*)d_in[6];
  float* out = (float*)d_out;

  f16* qlr = (f16*)d_ws;                                   // 4 MiB
  f16* klr = qlr + (size_t)B_ * H_ * T_ * R_;              // 4 MiB
  f16* vt  = klr + (size_t)B_ * H_ * T_ * R_;              // 8 MiB

  proj_kernel<<<B_ * H_ * NT, 256, 0, stream>>>(q, k, v, Wq, Wk, c1, c2, qlr, klr, vt);
  attn_kernel<<<B_ * H_ * NT, 256, 0, stream>>>(qlr, klr, vt, out);
}

// Round 10
// 138.555 us; speedup vs baseline: 5.7134x; 1.0234x over previous
//
#include <hip/hip_runtime.h>

typedef _Float16 f16;
typedef _Float16 f16x2 __attribute__((ext_vector_type(2)));
typedef _Float16 f16x4 __attribute__((ext_vector_type(4)));
typedef _Float16 f16x8 __attribute__((ext_vector_type(8)));
typedef float    f32x4 __attribute__((ext_vector_type(4)));

constexpr int B_ = 2, H_ = 16, T_ = 2048, D_ = 64, R_ = 32, NT = 32;
constexpr int NROW = B_ * H_ * T_;   // 65536 (bh,t) rows

__device__ __forceinline__ f32x4 mfma16(f16x8 a, f16x8 b, f32x4 c) {
  return __builtin_amdgcn_mfma_f32_16x16x32_f16(a, b, c, 0, 0, 0);
}
__device__ __forceinline__ void ld_lds16(const void* g, void* l) {
  __builtin_amdgcn_global_load_lds(
      (const __attribute__((address_space(1))) unsigned int*)g,
      (__attribute__((address_space(3))) unsigned int*)l, 16, 0, 0);
}

// ---------------- Kernel A: MFMA projections + swizzled V^T (R7 verbatim) ----------------
__global__ __launch_bounds__(256) void proj_kernel(
    const float* __restrict__ q, const float* __restrict__ k, const float* __restrict__ v,
    const float* __restrict__ Wq, const float* __restrict__ Wk,
    const float* __restrict__ c1, const float* __restrict__ c2,
    f16* __restrict__ qlr, f16* __restrict__ klr, f16* __restrict__ vt)
{
  __shared__ float sv[64 * 65];                    // 16.6 KB V transpose
  __shared__ __align__(16) f16 s_w[2][32 * 64];    //  8 KB W^T [mat][r][d-swz]
  __shared__ __align__(16) f16 s_qk[2][64 * 32];   //  8 KB [mat][row][r]

  const int tid = threadIdx.x, w = tid >> 6, lane = tid & 63;
  const int l15 = lane & 15, l4 = lane >> 4;
  const int bh = blockIdx.x >> 5, h = bh & (H_ - 1);
  const int t0 = (blockIdx.x & 31) * 64;

  const float* vb = v + ((size_t)bh * T_ + t0) * D_;
  float4 vld[4];
#pragma unroll
  for (int it = 0; it < 4; ++it) vld[it] = ((const float4*)vb)[it * 256 + tid];

  const int m = t0 + 16 * w + l15;
  const float* qr = q + ((size_t)bh * T_ + m) * D_;
  const float* kr = k + ((size_t)bh * T_ + m) * D_;
  f16x8 aq[2], ak[2];
#pragma unroll
  for (int kc = 0; kc < 2; ++kc) {
    float4 x0 = *(const float4*)(qr + kc * 32 + 8 * l4);
    float4 x1 = *(const float4*)(qr + kc * 32 + 8 * l4 + 4);
    float4 y0 = *(const float4*)(kr + kc * 32 + 8 * l4);
    float4 y1 = *(const float4*)(kr + kc * 32 + 8 * l4 + 4);
    f16x8 A, K;
    A[0]=(f16)x0.x; A[1]=(f16)x0.y; A[2]=(f16)x0.z; A[3]=(f16)x0.w;
    A[4]=(f16)x1.x; A[5]=(f16)x1.y; A[6]=(f16)x1.z; A[7]=(f16)x1.w;
    K[0]=(f16)y0.x; K[1]=(f16)y0.y; K[2]=(f16)y0.z; K[3]=(f16)y0.w;
    K[4]=(f16)y1.x; K[5]=(f16)y1.y; K[6]=(f16)y1.z; K[7]=(f16)y1.w;
    aq[kc] = A; ak[kc] = K;
  }

  // ---- W -> LDS, transposed + swizzled: elem (r,d) at r*64 + ((d>>3)^(r&7))*8 + (d&7)
  const float* Wqh = Wq + (size_t)h * D_ * R_;
  const float* Wkh = Wk + (size_t)h * D_ * R_;
#pragma unroll
  for (int mm = 0; mm < 2; ++mm) {
    const float* Wh = mm ? Wkh : Wqh;
#pragma unroll
    for (int it = 0; it < 2; ++it) {
      const int flat = it * 1024 + tid * 4;        // = d*32 + r, 4 consecutive r
      const int d = flat >> 5, r = flat & 31;
      const float4 wv = *(const float4*)(Wh + flat);
#pragma unroll
      for (int e = 0; e < 4; ++e) {
        const int rr = r + e;
        s_w[mm][rr * 64 + ((((d >> 3) ^ (rr & 7)) << 3) | (d & 7))] = (f16)((&wv.x)[e]);
      }
    }
  }

#pragma unroll
  for (int it = 0; it < 4; ++it) {
    const int i4 = it * 256 + tid, t = i4 >> 4, dq = (i4 & 15) * 4;
    sv[t * 65 + dq    ] = vld[it].x;
    sv[t * 65 + dq + 1] = vld[it].y;
    sv[t * 65 + dq + 2] = vld[it].z;
    sv[t * 65 + dq + 3] = vld[it].w;
  }

  __syncthreads();   // covers s_w and sv

  f16x8 bq[2][2], bk[2][2];
#pragma unroll
  for (int kc = 0; kc < 2; ++kc)
#pragma unroll
    for (int nt = 0; nt < 2; ++nt) {
      const int r = 16 * nt + l15;
      const int d0 = kc * 32 + 8 * l4;
      const int idx = r * 64 + (((d0 >> 3) ^ (r & 7)) << 3);
      bq[kc][nt] = *(const f16x8*)&s_w[0][idx];
      bk[kc][nt] = *(const f16x8*)&s_w[1][idx];
    }

  const f32x4 z4 = {0.f, 0.f, 0.f, 0.f};
#pragma unroll
  for (int nt = 0; nt < 2; ++nt) {
    f32x4 accq = mfma16(aq[0], bq[0][nt], z4);
    accq = mfma16(aq[1], bq[1][nt], accq);
    f32x4 acck = mfma16(ak[0], bk[0][nt], z4);
    acck = mfma16(ak[1], bk[1][nt], acck);
    const int r = 16 * nt + l15;
    const float scl = c1[h * 4 + (r >> 3)] * c2[h * 8 + (r & 7)] *
                      (0.17677669529663687f * 1.4426950408889634f);
#pragma unroll
    for (int i = 0; i < 4; ++i) {
      const int lrow = 16 * w + 4 * l4 + i;          // local row 0..63
      s_qk[0][lrow * 32 + r] = (f16)(accq[i] * scl);
      s_qk[1][lrow * 32 + r] = (f16)acck[i];
    }
  }

  // vt stores (read sv; safe after first barrier)
#pragma unroll
  for (int it = 0; it < 8; ++it) {
    const int idx = it * 256 + tid, d = idx >> 5, t = (idx & 31) * 2;
    const float f0 = sv[t * 65 + d], f1 = sv[t * 65 + 65 + d];
    f16x2 pr; pr[0] = (f16)f0; pr[1] = (f16)f1;
    const int sw = ((((t >> 3) ^ (d & 7)) << 3) | (t & 7));
    *(f16x2*)(vt + ((size_t)bh * D_ + d) * T_ + t0 + sw) = pr;
  }

  __syncthreads();   // covers s_qk

  const int lrow = tid >> 2;
  const int r0 = (tid & 3) * 8;
  const f16x8 vq = *(const f16x8*)&s_qk[0][lrow * 32 + r0];
  *(f16x8*)(qlr + ((size_t)bh * T_ + t0 + lrow) * R_ + r0) = vq;
  const f16x8 vk = *(const f16x8*)&s_qk[1][lrow * 32 + r0];
  *(f16x8*)(klr + ((size_t)bh * T_ + t0 + lrow) * R_ + r0) = vk;
}

// ---------------- Kernel B: flash attention, 128-col KV steps ----------------
// R9 analysis: with 1024 blocks = 4/CU all-resident, CU makespan = longest
// slot's SERIAL ITERATION COUNT (25-32), ~2x the 16.5 avg; and R0-R6 showed
// the per-iteration wall is latency-set, nearly independent of per-iter work.
// So: process TWO j-tiles (128 KV cols) per iteration -> serial depth halves
// (mt=31: 32->16 iters), per-iter wall grows sub-2x (one barrier pair / one
// max-reduce / one rescale per 2 tiles). vt's 128 consecutive cols are
// contiguous bytes (per-64 swizzle baked in) so staging stays ld_lds16;
// P/V swizzle applied per-64 tile (+64*tt on store & read sides).
// LDS 40KB = exactly 4 blocks/CU (same residency as R9). m-split only,
// direct f32 out (R8 lesson: no intra-kernel cross-XCD merge).
// No min-waves launch_bounds (R2 spill lesson).
__global__ __launch_bounds__(256) void attn_kernel(
    const f16* __restrict__ qlr, const f16* __restrict__ klr,
    const f16* __restrict__ vt, float* __restrict__ out)
{
  __shared__ __align__(16) f16 s_k[128 * 32];       //  8KB [n][r], n 0..127
  __shared__ __align__(16) f16 s_vt[64 * 128];      // 16KB [d][2x64 swizzled]
  __shared__ __align__(16) f16 s_p[4][16 * 128];    // 16KB per-wave [m][2x64 swz]

  const int tid = threadIdx.x, w = tid >> 6, lane = tid & 63;
  const int l15 = lane & 15, l4 = lane >> 4;
  const int bh = blockIdx.x & 31;
  const int mt = 31 - (blockIdx.x >> 5);   // longest-first dispatch
  const int m0 = mt * 64;

  // wave w owns m-rows [m0+16w, m0+16w+16); per-lane m = l15 (4 l4-dup groups)
  const f16x8 aq = *(const f16x8*)(qlr + ((size_t)bh * T_ + m0 + 16 * w + l15) * R_ + 8 * l4);

  const f16* kb = klr + (size_t)bh * T_ * R_;
  const f16* vb = vt + (size_t)bh * D_ * T_;

  const f32x4 z4 = {0.f, 0.f, 0.f, 0.f};
  f32x4 oacc[4];
#pragma unroll
  for (int d = 0; d < 4; ++d) oacc[d] = z4;
  float mi = -1e30f, li = 0.f;

  for (int jj = 0; jj <= mt; jj += 2) {
    const int n0 = 64 * jj;                // 128 cols: n0 .. n0+127
    __syncthreads();
    // stage K rows n0..n0+127 (8KB): wave w covers rows 32w..32w+31
#pragma unroll
    for (int e = 0; e < 2; ++e)
      ld_lds16((const char*)kb + (size_t)n0 * 64 + w * 2048 + e * 1024 + lane * 16,
               (char*)s_k + w * 2048 + e * 1024);
    // stage V^T 128 cols (16KB): wave w covers d = 16w..16w+15, 4x(4 rows x 256B)
#pragma unroll
    for (int e = 0; e < 4; ++e) {
      const int d0 = 16 * w + 4 * e;
      ld_lds16((const char*)vb + ((size_t)(d0 + (lane >> 4)) * T_ + n0) * 2 + (lane & 15) * 16,
               (char*)s_vt + d0 * 256);
    }
    __syncthreads();

    // QK^T: sc[ns][i] = score(n_local = 16ns+4l4+i, m = l15), ns 0..7
    f32x4 sc[8];
#pragma unroll
    for (int ns = 0; ns < 8; ++ns) {
      f16x8 akf = *(const f16x8*)&s_k[(16 * ns + l15) * 32 + 8 * l4];
      sc[ns] = mfma16(akf, aq, z4);
    }
    if (jj + 2 > mt) {                      // diagonal (last) iteration
      const int lim = (m0 - n0) + 16 * w + l15;   // mask n_local > lim
#pragma unroll
      for (int ns = 0; ns < 8; ++ns) {
        const int nb = 16 * ns + 4 * l4;
#pragma unroll
        for (int i = 0; i < 4; ++i)
          if (nb + i > lim) sc[ns][i] = -1e30f;
      }
    }

    float rm = -1e30f;
#pragma unroll
    for (int ns = 0; ns < 8; ++ns)
#pragma unroll
      for (int i = 0; i < 4; ++i) rm = fmaxf(rm, sc[ns][i]);
    rm = fmaxf(rm, __shfl_xor(rm, 16));
    rm = fmaxf(rm, __shfl_xor(rm, 32));
    const float mn = fmaxf(mi, rm);
    const float a = exp2f(mi - mn);
    float rs = 0.f;
#pragma unroll
    for (int ns = 0; ns < 8; ++ns) {
      f16x4 pf;
#pragma unroll
      for (int i = 0; i < 4; ++i) {
        const float p = exp2f(sc[ns][i] - mn);
        rs += p; pf[i] = (f16)p;
      }
      // per-64-tile XOR swizzle, tile tt = ns>>2, local group ns&3
      const int col = 64 * (ns >> 2) +
                      ((((2 * (ns & 3) + (l4 >> 1)) ^ (l15 & 7)) << 3) | (4 * (l4 & 1)));
      *(f16x4*)&s_p[w][l15 * 128 + col] = pf;
    }
    rs += __shfl_xor(rs, 16);
    rs += __shfl_xor(rs, 32);
    li = li * a + rs; mi = mn;
#pragma unroll
    for (int d = 0; d < 4; ++d) oacc[d] *= a;

    // PV over both 64-col tiles: un-swizzle per tile (u within tile)
#pragma unroll
    for (int tt = 0; tt < 2; ++tt)
#pragma unroll
      for (int nk = 0; nk < 2; ++nk) {
        const int u = (4 * nk + l4) ^ (l15 & 7);
        f16x8 bp = *(const f16x8*)&s_p[w][l15 * 128 + 64 * tt + u * 8];
#pragma unroll
        for (int dblk = 0; dblk < 4; ++dblk) {
          f16x8 av = *(const f16x8*)&s_vt[(16 * dblk + l15) * 128 + 64 * tt + u * 8];
          oacc[dblk] = mfma16(av, bp, oacc[dblk]);
        }
      }
  }

  // ---- epilogue: final normalize, direct f32 output ----
  const float invl = li > 0.f ? 1.f / li : 0.f;
  float* ob = out + ((size_t)bh * T_ + m0 + 16 * w + l15) * D_;
#pragma unroll
  for (int dblk = 0; dblk < 4; ++dblk) {
    f32x4 o;
#pragma unroll
    for (int i = 0; i < 4; ++i) o[i] = oacc[dblk][i] * invl;
    *(f32x4*)(ob + 16 * dblk + 4 * l4) = o;
  }
}

extern "C" void kernel_launch(void* const* d_in, const int* in_sizes, int n_in,
                              void* d_out, int out_size, void* d_ws, size_t ws_size,
                              hipStream_t stream) {
  const float* q  = (const float*)d_in[0];
  const float* k  = (const float*)d_in[1];
  const float* v  = (const float*)d_in[2];
  const float* Wq = (const float*)d_in[3];
  const float* Wk = (const float*)d_in[4];
  const float* c1 = (const float*)d_in[5];
  const float* c2 = (const float*)d_in[6];
  float* out = (float*)d_out;

  f16* qlr = (f16*)d_ws;                                   // 4 MiB
  f16* klr = qlr + (size_t)B_ * H_ * T_ * R_;              // 4 MiB
  f16* vt  = klr + (size_t)B_ * H_ * T_ * R_;              // 8 MiB

  proj_kernel<<<B_ * H_ * NT, 256, 0, stream>>>(q, k, v, Wq, Wk, c1, c2, qlr, klr, vt);
  attn_kernel<<<B_ * H_ * NT, 256, 0, stream>>>(qlr, klr, vt, out);
}